// Round 3
// baseline (500.499 us; speedup 1.0000x reference)
//
#include <hip/hip_runtime.h>
#include <hip/hip_cooperative_groups.h>
#include <cstdint>
#include <cstddef>

namespace cgrp = cooperative_groups;

#define N_ANCH   120000
#define K_PRE    2000
#define K_POST   512
#define CAP      4096
#define NWORD    32          // ceil(K_PRE/64)
#define HBINS    4096        // top-12-bit histogram
#define IOU_THR  0.7f
#define IMGF     800.0f
#define CLIPV    4.135166556742356f
#define FH       200
#define FW       200
#define FC       256
#define SCALE    0.25f

#define TROWS    96          // scan tile rows (96*256B = 24KB; x2 buffers = 48KB LDS)
#define NTILE    21          // ceil(2000/96); last tile = 80 rows
#define CH       8           // scan chunk rows (register prefetch depth)

#define CG       16          // roi: channels per group (FC/16 -> two time-phased groups per XCD)
#define TPE      4           // rank: threads per element

typedef unsigned long long u64;
// float2 with declared 4B alignment: compiler emits dwordx2; gfx9+ amdhsa
// unaligned-access-mode handles 4B-aligned 8B loads in HW.
typedef float f2u __attribute__((ext_vector_type(2), aligned(4)));

struct Ws {
    uint32_t T;          // (unused — kept for layout stability)
    uint32_t cnt;        // gather counter
    int32_t  nk;         // number kept after NMS
    uint32_t pad;
    u64      combo[CAP];             // (~key)<<32 | index (unsorted)
    float4   cand[K_PRE];            // decoded candidate boxes, score-desc order
    int      rows[K_POST];           // candidate rank per output row, -1 = invalid
    u64      mask[(size_t)K_PRE * NWORD];  // IoU bitmask, ALL 32 words written
    // NOTE: first 16KB of mask doubles as the uint32 hist[4096] (used before mask)
};

// Monotonic float -> uint key (larger float => larger uint). No NaNs expected.
__device__ inline uint32_t fkey(float f) {
    uint32_t u = __float_as_uint(f);
    return (u & 0x80000000u) ? ~u : (u | 0x80000000u);
}

// LDS is time-shared across phases (grid.sync separates uses).
union __align__(16) Smem {
    uint32_t hist[HBINS];                               // phase B: 16 KB
    struct { uint32_t wsum[4]; uint32_t sT; } res;      // phase C
    u64 sc[CAP];                                        // phase D: 32 KB
    struct { u64 buf[2][TROWS * NWORD]; int stop; } scan; // phase F: 48 KB
};

// ---------------------------------------------------------------------------
// Round-13: ONE cooperative kernel replaces the 7-kernel pipeline.
// Rationale: rounds 0-2 show (total - roi) pinned at ~151us while all
// non-roi kernels sum to ~40us of compute — the remainder is per-node
// dispatch overhead (13 nodes/iter x ~8us). Fusing to a single node with
// grid.sync() between phases removes ~6 kernel-node overheads at the cost
// of ~6 in-kernel grid barriers.
// Grid: 3 blocks/CU x 256 CUs = 768 (from occupancy API at launch; LDS
// union 48KB -> exactly 3/CU; launch_bounds(256,3) caps VGPR accordingly).
// All phases grid-strided; 768 % 8 == 0 keeps the roi XCD swizzle intact.
// ---------------------------------------------------------------------------
__global__ __launch_bounds__(256, 3) void fused_k(const float* __restrict__ feat,
                                                  const float* __restrict__ obj,
                                                  const float* __restrict__ deltas,
                                                  const float* __restrict__ anchors,
                                                  Ws* __restrict__ ws,
                                                  float* __restrict__ out) {
    cgrp::grid_group grid = cgrp::this_grid();
    __shared__ Smem sm;
    const int tid  = threadIdx.x;
    const int bid  = blockIdx.x;
    const int NB   = gridDim.x;
    const int lane = tid & 63;
    const int wave = tid >> 6;
    uint32_t* hist = (uint32_t*)ws->mask;   // alias: hist lives in (pre-)mask space

    // ================= A: zero hist + counters =================
    for (int i = bid * 256 + tid; i < HBINS; i += NB * 256) hist[i] = 0u;
    if (bid == 0 && tid == 0) { ws->cnt = 0u; ws->nk = 0; }
    grid.sync();

    // ================= B: LDS-privatized histogram =================
    {
        for (int i = tid; i < HBINS; i += 256) sm.hist[i] = 0u;
        __syncthreads();
        const float4* o4 = (const float4*)obj;
        for (int i = bid * 256 + tid; i < N_ANCH / 4; i += NB * 256) {
            float4 v = o4[i];
            atomicAdd(&sm.hist[fkey(v.x) >> 20], 1u);
            atomicAdd(&sm.hist[fkey(v.y) >> 20], 1u);
            atomicAdd(&sm.hist[fkey(v.z) >> 20], 1u);
            atomicAdd(&sm.hist[fkey(v.w) >> 20], 1u);
        }
        __syncthreads();
        for (int i = tid; i < HBINS; i += 256)
            if (sm.hist[i]) atomicAdd(&hist[i], sm.hist[i]);
    }
    grid.sync();

    // ================= C: per-block threshold resolve + gather =================
    if (bid * 256 < N_ANCH / 4) {         // only blocks that own a gather slice
        uint32_t c[16]; uint32_t s = 0;
#pragma unroll
        for (int k = 0; k < 16; ++k) { c[k] = hist[HBINS - 1 - (16 * tid + k)]; s += c[k]; }
        uint32_t incl = s;
        for (int off = 1; off < 64; off <<= 1) {
            uint32_t t = __shfl_up(incl, off);
            if (lane >= off) incl += t;
        }
        if (lane == 63) sm.res.wsum[wave] = incl;
        __syncthreads();
        uint32_t wpre = 0;
        for (int w2 = 0; w2 < wave; ++w2) wpre += sm.res.wsum[w2];
        uint32_t before = wpre + incl - s;
#pragma unroll
        for (int k = 0; k < 16; ++k) {
            uint32_t after = before + c[k];
            if (before < K_PRE && after >= K_PRE)
                sm.res.sT = (uint32_t)(HBINS - 1 - (16 * tid + k)) << 20;
            before = after;
        }
        __syncthreads();
        const uint32_t T = sm.res.sT;
        const int i = bid * 256 + tid;
        if (i < N_ANCH / 4) {
            float4 v = ((const float4*)obj)[i];
            float vals[4] = {v.x, v.y, v.z, v.w};
#pragma unroll
            for (int k = 0; k < 4; ++k) {
                uint32_t u = fkey(vals[k]);
                if (u >= T) {
                    uint32_t pos = atomicAdd(&ws->cnt, 1u);
                    if (pos < CAP)
                        ws->combo[pos] = ((u64)(~u) << 32) | (uint32_t)(4 * i + k);
                }
            }
        }
    }
    grid.sync();

    // ================= D: rank + decode (blocks 0..63) =================
    if (bid < CAP / (256 / TPE)) {
        int M = (int)ws->cnt;
        if (M > CAP) M = CAP;
        const int ebase = bid * (256 / TPE);
        if (ebase < M) {
            for (int e = tid; e < M; e += 256) sm.sc[e] = ws->combo[e];
            __syncthreads();
            const int gid = ebase + tid / TPE;
            const int sub = tid & (TPE - 1);
            if (gid < M) {
                const u64 mine = sm.sc[gid];
                int cnt = 0;
                int j = sub;
                for (; j + 3 * TPE < M; j += 4 * TPE) {
                    u64 a = sm.sc[j], b = sm.sc[j + TPE];
                    u64 c2 = sm.sc[j + 2 * TPE], d = sm.sc[j + 3 * TPE];
                    cnt += (int)(a < mine) + (int)(b < mine) + (int)(c2 < mine) + (int)(d < mine);
                }
                for (; j < M; j += TPE) cnt += (int)(sm.sc[j] < mine);
                cnt += __shfl_xor(cnt, 1);
                cnt += __shfl_xor(cnt, 2);
                if (sub == 0 && cnt < K_PRE) {
                    const uint32_t idx = (uint32_t)(mine & 0xFFFFFFFFull);
                    float a0 = anchors[idx * 4 + 0], a1 = anchors[idx * 4 + 1];
                    float a2 = anchors[idx * 4 + 2], a3 = anchors[idx * 4 + 3];
                    float d0 = deltas[idx * 4 + 0],  d1 = deltas[idx * 4 + 1];
                    float d2 = fminf(deltas[idx * 4 + 2], CLIPV);
                    float d3 = fminf(deltas[idx * 4 + 3], CLIPV);
                    float w = a2 - a0, h = a3 - a1;
                    float cx = a0 + 0.5f * w, cy = a1 + 0.5f * h;
                    float pcx = d0 * w + cx, pcy = d1 * h + cy;
                    float pw = expf(d2) * w, ph = expf(d3) * h;
                    float x1 = fminf(fmaxf(pcx - 0.5f * pw, 0.0f), IMGF);
                    float y1 = fminf(fmaxf(pcy - 0.5f * ph, 0.0f), IMGF);
                    float x2 = fminf(fmaxf(pcx + 0.5f * pw, 0.0f), IMGF);
                    float y2 = fminf(fmaxf(pcy + 0.5f * ph, 0.0f), IMGF);
                    ws->cand[cnt] = make_float4(x1, y1, x2, y2);
                }
            }
        }
    }
    grid.sync();

    // ================= E: pairwise suppression bitmask =================
    for (int i = bid; i < K_PRE; i += NB) {
        const float4 bi = ws->cand[i];
        const float ai = (bi.z - bi.x) * (bi.w - bi.y);
        for (int wd = wave; wd < NWORD; wd += 4) {
            int j = wd * 64 + lane;
            bool bit = false;
            if (j < K_PRE && j > i) {
                float4 bj = ws->cand[j];
                float aj = (bj.z - bj.x) * (bj.w - bj.y);
                float xx1 = fmaxf(bi.x, bj.x);
                float yy1 = fmaxf(bi.y, bj.y);
                float xx2 = fminf(bi.z, bj.z);
                float yy2 = fminf(bi.w, bj.w);
                float ww = fmaxf(xx2 - xx1, 0.0f);
                float hh = fmaxf(yy2 - yy1, 0.0f);
                float inter = ww * hh;
                float iou = inter / (ai + aj - inter + 1e-6f);
                bit = iou > IOU_THR;
            }
            u64 bal = __ballot(bit);
            if (lane == 0) ws->mask[(size_t)i * NWORD + wd] = bal;
        }
    }
    grid.sync();

    // ================= F: greedy scan (block 0; 256 threads) =================
    if (bid == 0) {
        const int lmod = lane & 31;
        const u64* __restrict__ mask = ws->mask;
        {
            const ulonglong2* src = (const ulonglong2*)mask;
            ulonglong2* dst = (ulonglong2*)sm.scan.buf[0];
            for (int e = tid; e < TROWS * NWORD / 2; e += 256) dst[e] = src[e];
        }
        if (tid == 0) sm.scan.stop = 0;
        __syncthreads();

        u64 supp = 0ull;
        int kcnt = 0;
        int decided = 0;
        for (int t = 0; t < NTILE; ++t) {
            const int base = t * TROWS;
            const int nb = min(TROWS, K_PRE - base);
            if (wave == 0) {
                const u64* smb = sm.scan.buf[t & 1];
                u64 A[CH], B[CH];
#pragma unroll
                for (int b = 0; b < CH; ++b) A[b] = smb[b * NWORD + lmod];
                for (int s = 0; s < nb; s += 2 * CH) {
                    const bool hasB = (s + CH) < nb;
                    if (hasB) {
#pragma unroll
                        for (int b = 0; b < CH; ++b) B[b] = smb[(s + CH + b) * NWORD + lmod];
                    }
                    {
                        const int w = (base + s) >> 6;
                        const int bofs = (base + s) & 63;
                        u64 keptw = 0ull;
                        if (lane == w) {
                            u64 cur = supp;
#pragma unroll
                            for (int b = 0; b < CH; ++b) {
                                u64 bit = (cur >> (bofs + b)) & 1ull;
                                u64 sel = bit - 1ull;
                                cur |= A[b] & sel;
                                keptw |= sel & (1ull << b);
                            }
                            supp = cur;
                        }
                        u64 kb = __shfl(keptw, w);
                        kcnt += __popcll(kb);
#pragma unroll
                        for (int b = 0; b < CH; ++b) {
                            u64 sel = 0ull - ((kb >> b) & 1ull);
                            supp |= A[b] & sel;
                        }
                    }
                    if (hasB) {
                        if (s + 2 * CH < nb) {
#pragma unroll
                            for (int b = 0; b < CH; ++b)
                                A[b] = smb[(s + 2 * CH + b) * NWORD + lmod];
                        }
                        const int w = (base + s + CH) >> 6;
                        const int bofs = (base + s + CH) & 63;
                        u64 keptw = 0ull;
                        if (lane == w) {
                            u64 cur = supp;
#pragma unroll
                            for (int b = 0; b < CH; ++b) {
                                u64 bit = (cur >> (bofs + b)) & 1ull;
                                u64 sel = bit - 1ull;
                                cur |= B[b] & sel;
                                keptw |= sel & (1ull << b);
                            }
                            supp = cur;
                        }
                        u64 kb = __shfl(keptw, w);
                        kcnt += __popcll(kb);
#pragma unroll
                        for (int b = 0; b < CH; ++b) {
                            u64 sel = 0ull - ((kb >> b) & 1ull);
                            supp |= B[b] & sel;
                        }
                    }
                }
                decided = base + nb;
                if (lane == 0 && kcnt >= K_POST) sm.scan.stop = 1;
            } else if (t + 1 < NTILE) {
                const int nbase = (t + 1) * TROWS;
                const int npairs = (min(TROWS, K_PRE - nbase) * NWORD) / 2;
                const ulonglong2* src = (const ulonglong2*)(mask + (size_t)nbase * NWORD);
                ulonglong2* dst = (ulonglong2*)sm.scan.buf[(t + 1) & 1];
                for (int e = tid - 64; e < npairs; e += 192) dst[e] = src[e];
            }
            __syncthreads();
            if (sm.scan.stop) break;
        }

        if (wave == 0) {
            u64 valid;
            if (lane < NWORD - 1)       valid = ~0ull;
            else if (lane == NWORD - 1) valid = (1ull << (K_PRE - (NWORD - 1) * 64)) - 1ull;
            else                        valid = 0ull;
            const int dw = decided - lane * 64;
            const u64 dmask = (dw <= 0) ? 0ull : ((dw >= 64) ? ~0ull : ((1ull << dw) - 1ull));
            u64 keepw = (~supp) & valid & dmask;
            int cnt = __popcll(keepw);
            int incl = cnt;
            for (int off = 1; off < 64; off <<= 1) {
                int t = __shfl_up(incl, off);
                if (lane >= off) incl += t;
            }
            int pos = incl - cnt;
            u64 kw = keepw;
            while (kw) {
                int b = __ffsll((unsigned long long)kw) - 1;
                kw &= kw - 1ull;
                if (pos < K_POST) ws->rows[pos] = lane * 64 + b;
                ++pos;
            }
            int total = __shfl(incl, 63);
            if (lane == 0) ws->nk = total;
            int start = total < K_POST ? total : K_POST;
            for (int r = start + lane; r < K_POST; r += 64) ws->rows[r] = -1;
        }
    }
    grid.sync();

    // ================= G: ROIAlign (round-12 body, grid-strided) =================
    for (int vb = bid; vb < 16 * K_POST; vb += NB) {
        const int xcd = vb & 7;             // NB % 8 == 0 -> constant per block
        const int sq = vb >> 3;
        const int r = sq & (K_POST - 1);
        const int cgi = xcd + 8 * (sq >> 9);
        const int cbase = cgi * CG;
        float* oblk = out + (size_t)r * (FC * 49) + (size_t)cbase * 49;
        const int row = ws->rows[r];

        if (row < 0) {
            for (int e = tid; e < CG * 49; e += 256) oblk[e] = 0.0f;
            continue;
        }
        if (tid >= 245) continue;           // 5 channel slots x 49 bins

        const int p = tid % 49;
        const int cslot = tid / 49;         // 0..4
        const int oy = p / 7, ox = p % 7;

        const float4 bx = ws->cand[row];
        const float x1 = bx.x * SCALE, y1 = bx.y * SCALE;
        const float x2 = bx.z * SCALE, y2 = bx.w * SCALE;
        const float rw = fmaxf(x2 - x1, 1.0f);
        const float rh = fmaxf(y2 - y1, 1.0f);
        const float stepx = rw / 14.0f;
        const float stepy = rh / 14.0f;

        int    off0[4], off1[4];
        float4 w4[4];
#pragma unroll
        for (int sub = 0; sub < 4; ++sub) {
            const int sy = sub >> 1, sx = sub & 1;
            float yy = y1 + ((float)(2 * oy + sy) + 0.5f) * stepy;
            float y = fminf(fmaxf(yy, 0.0f), (float)(FH - 1));
            float fy0 = floorf(y);
            int iy0 = (int)fy0;
            int iy1 = min(iy0 + 1, FH - 1);
            float ly = y - fy0;
            float xx = x1 + ((float)(2 * ox + sx) + 0.5f) * stepx;
            float x = fminf(fmaxf(xx, 0.0f), (float)(FW - 1));
            float fx0 = floorf(x);
            int ix0 = (int)fx0;
            float lx = x - fx0;
            float wxl, wxr; int base;
            if (ix0 >= FW - 1) { base = FW - 2; wxl = 0.0f; wxr = 1.0f; }
            else               { base = ix0;    wxl = 1.0f - lx; wxr = lx; }
            float wy0 = 1.0f - ly, wy1 = ly;
            off0[sub] = iy0 * FW + base;
            off1[sub] = iy1 * FW + base;
            w4[sub] = make_float4(wy0 * wxl * 0.25f, wy0 * wxr * 0.25f,
                                  wy1 * wxl * 0.25f, wy1 * wxr * 0.25f);
        }

        // ---- ISSUE PHASE: all scattered loads back-to-back.
        const float* fb = feat + (size_t)cbase * (FH * FW);
        const float* f0 = fb + (size_t)cslot * (FH * FW);
        const float* f1 = fb + (size_t)(cslot + 5) * (FH * FW);
        const float* f2 = fb + (size_t)(cslot + 10) * (FH * FW);
        f2u r0[8], r1[8], r2[8], r3[8];
#pragma unroll
        for (int sub = 0; sub < 4; ++sub) {
            r0[2 * sub]     = *(const f2u*)(f0 + off0[sub]);
            r0[2 * sub + 1] = *(const f2u*)(f0 + off1[sub]);
        }
#pragma unroll
        for (int sub = 0; sub < 4; ++sub) {
            r1[2 * sub]     = *(const f2u*)(f1 + off0[sub]);
            r1[2 * sub + 1] = *(const f2u*)(f1 + off1[sub]);
        }
#pragma unroll
        for (int sub = 0; sub < 4; ++sub) {
            r2[2 * sub]     = *(const f2u*)(f2 + off0[sub]);
            r2[2 * sub + 1] = *(const f2u*)(f2 + off1[sub]);
        }
        const bool has4 = (cslot == 0);
        if (has4) {
            const float* f3 = fb + (size_t)15 * (FH * FW);
#pragma unroll
            for (int sub = 0; sub < 4; ++sub) {
                r3[2 * sub]     = *(const f2u*)(f3 + off0[sub]);
                r3[2 * sub + 1] = *(const f2u*)(f3 + off1[sub]);
            }
        }

        // ---- COMPUTE PHASE: FMAs in load-issue order.
        float a0 = 0.0f, a1 = 0.0f, a2 = 0.0f;
#pragma unroll
        for (int sub = 0; sub < 4; ++sub) {
            a0 += w4[sub].x * r0[2 * sub].x + w4[sub].y * r0[2 * sub].y
                + w4[sub].z * r0[2 * sub + 1].x + w4[sub].w * r0[2 * sub + 1].y;
        }
#pragma unroll
        for (int sub = 0; sub < 4; ++sub) {
            a1 += w4[sub].x * r1[2 * sub].x + w4[sub].y * r1[2 * sub].y
                + w4[sub].z * r1[2 * sub + 1].x + w4[sub].w * r1[2 * sub + 1].y;
        }
#pragma unroll
        for (int sub = 0; sub < 4; ++sub) {
            a2 += w4[sub].x * r2[2 * sub].x + w4[sub].y * r2[2 * sub].y
                + w4[sub].z * r2[2 * sub + 1].x + w4[sub].w * r2[2 * sub + 1].y;
        }
        oblk[cslot * 49 + p] = a0;
        oblk[(cslot + 5) * 49 + p] = a1;
        oblk[(cslot + 10) * 49 + p] = a2;

        if (has4) {
            float a3 = 0.0f;
#pragma unroll
            for (int sub = 0; sub < 4; ++sub) {
                a3 += w4[sub].x * r3[2 * sub].x + w4[sub].y * r3[2 * sub].y
                    + w4[sub].z * r3[2 * sub + 1].x + w4[sub].w * r3[2 * sub + 1].y;
            }
            oblk[15 * 49 + p] = a3;
        }
    }
}

extern "C" void kernel_launch(void* const* d_in, const int* in_sizes, int n_in,
                              void* d_out, int out_size, void* d_ws, size_t ws_size,
                              hipStream_t stream) {
    const float* feature    = (const float*)d_in[0];
    const float* objectness = (const float*)d_in[1];
    const float* deltas     = (const float*)d_in[2];
    const float* anchors    = (const float*)d_in[3];
    Ws* ws = (Ws*)d_ws;
    float* out = (float*)d_out;

    // Grid sizing: co-resident capacity from the occupancy API (expected 3
    // blocks/CU: LDS union 48KB -> 3; launch_bounds(256,3) caps VGPR).
    // Cached: host-only query, graph-capture-safe.
    static int s_grid = 0;
    if (s_grid == 0) {
        int nb = 0;
        if (hipOccupancyMaxActiveBlocksPerMultiprocessor(&nb, fused_k, 256, 0) != hipSuccess || nb < 1)
            nb = 1;
        if (nb > 3) nb = 3;
        int ncu = 256;
        hipDeviceProp_t prop;
        if (hipGetDeviceProperties(&prop, 0) == hipSuccess && prop.multiProcessorCount > 0)
            ncu = prop.multiProcessorCount;
        s_grid = (nb * ncu) & ~7;          // multiple of 8 for the XCD swizzle
        if (s_grid < 8) s_grid = 8;
    }

    void* args[] = {(void*)&feature, (void*)&objectness, (void*)&deltas,
                    (void*)&anchors, (void*)&ws, (void*)&out};
    hipLaunchCooperativeKernel(fused_k, dim3(s_grid), dim3(256), args, 0, stream);
}

// Round 4
// 252.137 us; speedup vs baseline: 1.9850x; 1.9850x over previous
//
#include <hip/hip_runtime.h>
#include <cstdint>
#include <cstddef>

#define N_ANCH   120000
#define K_PRE    2000
#define K_POST   512
#define CAP      4096
#define NWORD    32          // ceil(K_PRE/64)
#define HBINS    4096        // top-12-bit histogram
#define IOU_THR  0.7f
#define IMGF     800.0f
#define CLIPV    4.135166556742356f
#define FH       200
#define FW       200
#define FC       256
#define SCALE    0.25f

#define TROWS    96          // scan tile rows (96*256B = 24KB; x2 buffers = 48KB LDS)
#define NTILE    21          // ceil(2000/96); last tile = 80 rows
#define CH       8           // scan chunk rows (register prefetch depth)

#define CG       16          // roi: channels per group (two time-phased groups per XCD)
#define TPE      4           // rank: threads per element
#define SEL_NB   128         // sel_k blocks (<=256 -> co-resident, spin-safe)

typedef unsigned long long u64;
typedef float f2u __attribute__((ext_vector_type(2), aligned(4)));

struct Ws {
    uint32_t T;          // ticket counter for mask->scan last-block handoff
    uint32_t cnt;        // gather counter
    int32_t  nk;         // number kept after NMS
    uint32_t pad;
    u64      combo[CAP];             // (~key)<<32 | index (unsorted)
    float4   cand[K_PRE];            // decoded candidate boxes, score-desc order
    int      rows[K_POST];           // candidate rank per output row, -1 = invalid
    u64      mask[(size_t)K_PRE * NWORD];  // IoU bitmask
    // mask[0..HBINS) (u32 view) = hist; mask u32[HBINS..HBINS+3) = barrier ctrs
};

// Monotonic float -> uint key (larger float => larger uint). No NaNs expected.
__device__ inline uint32_t fkey(float f) {
    uint32_t u = __float_as_uint(f);
    return (u & 0x80000000u) ? ~u : (u | 0x80000000u);
}

// Lightweight device barrier for co-resident grids. One atomic arrival per
// block + relaxed polling by lane 0 only; threadfence pair gives the same
// release/acquire a kernel boundary would. NO s_sleep storm, no full-grid
// coop machinery (round-3's grid.sync measured ~70-90us/barrier — refuted).
__device__ inline void dbar(uint32_t* ctr, uint32_t nb) {
    __syncthreads();
    if (threadIdx.x == 0) {
        __threadfence();                 // release my global writes
        atomicAdd(ctr, 1u);
        while (__hip_atomic_load(ctr, __ATOMIC_RELAXED, __HIP_MEMORY_SCOPE_AGENT) < nb)
            __builtin_amdgcn_s_sleep(2);
        __threadfence();                 // acquire others' writes
    }
    __syncthreads();
}

// LDS union for sel_k phases (time-separated by barriers/syncthreads).
union __align__(16) SelSmem {
    uint32_t hist[HBINS];                           // 16 KB
    struct { uint32_t wsum[4]; uint32_t sT; } res;
    u64 sc[CAP];                                    // 32 KB
};

// ---------------------------------------------------------------------------
// Kernel 1 (round-4): fused {zero, hist, gather, rank_decode}. 128 blocks,
// 3 custom barriers. Replaces 4 kernel nodes with 1.
// ---------------------------------------------------------------------------
__global__ __launch_bounds__(256) void sel_k(const float* __restrict__ obj,
                                             const float* __restrict__ deltas,
                                             const float* __restrict__ anchors,
                                             Ws* __restrict__ ws) {
    __shared__ SelSmem sm;
    const int tid  = threadIdx.x;
    const int bid  = blockIdx.x;
    const int lane = tid & 63;
    const int wave = tid >> 6;
    uint32_t* hist = (uint32_t*)ws->mask;
    uint32_t* bctr = hist + HBINS;       // 3 barrier counters (memset-zeroed)

    // ---- Z: zero global hist slice + header ----
    if (tid < HBINS / SEL_NB) hist[bid * (HBINS / SEL_NB) + tid] = 0u;
    if (bid == 0 && tid == 0) { ws->cnt = 0u; ws->T = 0u; }

    // ---- H: LDS-privatized histogram of this block's slice ----
    for (int i = tid; i < HBINS; i += 256) sm.hist[i] = 0u;
    __syncthreads();
    {
        const float4* o4 = (const float4*)obj;
        const int i = bid * 256 + tid;
        if (i < N_ANCH / 4) {
            float4 v = o4[i];
            atomicAdd(&sm.hist[fkey(v.x) >> 20], 1u);
            atomicAdd(&sm.hist[fkey(v.y) >> 20], 1u);
            atomicAdd(&sm.hist[fkey(v.z) >> 20], 1u);
            atomicAdd(&sm.hist[fkey(v.w) >> 20], 1u);
        }
    }
    __syncthreads();

    dbar(&bctr[0], SEL_NB);              // global hist zeroed everywhere

    // ---- flush LDS hist to global ----
    for (int i = tid; i < HBINS; i += 256)
        if (sm.hist[i]) atomicAdd(&hist[i], sm.hist[i]);

    dbar(&bctr[1], SEL_NB);              // global hist complete

    // ---- resolve threshold (per-block redundant) ----
    {
        uint32_t c[16]; uint32_t s = 0;
#pragma unroll
        for (int k = 0; k < 16; ++k) { c[k] = hist[HBINS - 1 - (16 * tid + k)]; s += c[k]; }
        uint32_t incl = s;
        for (int off = 1; off < 64; off <<= 1) {
            uint32_t t = __shfl_up(incl, off);
            if (lane >= off) incl += t;
        }
        __syncthreads();                 // sm.hist dead; res aliases it
        if (lane == 63) sm.res.wsum[wave] = incl;
        __syncthreads();
        uint32_t wpre = 0;
        for (int w2 = 0; w2 < wave; ++w2) wpre += sm.res.wsum[w2];
        uint32_t before = wpre + incl - s;
#pragma unroll
        for (int k = 0; k < 16; ++k) {
            uint32_t after = before + c[k];
            if (before < K_PRE && after >= K_PRE)
                sm.res.sT = (uint32_t)(HBINS - 1 - (16 * tid + k)) << 20;
            before = after;
        }
        __syncthreads();
        const uint32_t T = sm.res.sT;
        // ---- gather ----
        const int i = bid * 256 + tid;
        if (i < N_ANCH / 4) {
            float4 v = ((const float4*)obj)[i];
            float vals[4] = {v.x, v.y, v.z, v.w};
#pragma unroll
            for (int k = 0; k < 4; ++k) {
                uint32_t u = fkey(vals[k]);
                if (u >= T) {
                    uint32_t pos = atomicAdd(&ws->cnt, 1u);
                    if (pos < CAP)
                        ws->combo[pos] = ((u64)(~u) << 32) | (uint32_t)(4 * i + k);
                }
            }
        }
    }

    dbar(&bctr[2], SEL_NB);              // all combos written

    // ---- rank + decode (blocks 0..63 active) ----
    {
        int M = (int)ws->cnt;
        if (M > CAP) M = CAP;
        const int ebase = bid * (256 / TPE);
        if (ebase >= M) return;
        __syncthreads();                 // sm.res dead; sc aliases it
        for (int e = tid; e < M; e += 256) sm.sc[e] = ws->combo[e];
        __syncthreads();
        const int gid = ebase + tid / TPE;
        const int sub = tid & (TPE - 1);
        if (gid >= M) return;
        const u64 mine = sm.sc[gid];
        int cnt = 0;
        int j = sub;
        for (; j + 3 * TPE < M; j += 4 * TPE) {
            u64 a = sm.sc[j], b = sm.sc[j + TPE];
            u64 c2 = sm.sc[j + 2 * TPE], d = sm.sc[j + 3 * TPE];
            cnt += (int)(a < mine) + (int)(b < mine) + (int)(c2 < mine) + (int)(d < mine);
        }
        for (; j < M; j += TPE) cnt += (int)(sm.sc[j] < mine);
        cnt += __shfl_xor(cnt, 1);
        cnt += __shfl_xor(cnt, 2);
        if (sub == 0 && cnt < K_PRE) {
            const uint32_t idx = (uint32_t)(mine & 0xFFFFFFFFull);
            float a0 = anchors[idx * 4 + 0], a1 = anchors[idx * 4 + 1];
            float a2 = anchors[idx * 4 + 2], a3 = anchors[idx * 4 + 3];
            float d0 = deltas[idx * 4 + 0],  d1 = deltas[idx * 4 + 1];
            float d2 = fminf(deltas[idx * 4 + 2], CLIPV);
            float d3 = fminf(deltas[idx * 4 + 3], CLIPV);
            float w = a2 - a0, h = a3 - a1;
            float cx = a0 + 0.5f * w, cy = a1 + 0.5f * h;
            float pcx = d0 * w + cx, pcy = d1 * h + cy;
            float pw = expf(d2) * w, ph = expf(d3) * h;
            float x1 = fminf(fmaxf(pcx - 0.5f * pw, 0.0f), IMGF);
            float y1 = fminf(fmaxf(pcy - 0.5f * ph, 0.0f), IMGF);
            float x2 = fminf(fmaxf(pcx + 0.5f * pw, 0.0f), IMGF);
            float y2 = fminf(fmaxf(pcy + 0.5f * ph, 0.0f), IMGF);
            ws->cand[cnt] = make_float4(x1, y1, x2, y2);
        }
    }
}

// ---------------------------------------------------------------------------
// Kernel 2 (round-4): fused {nms_mask, nms_scan} via last-block ticket.
// 2000 blocks x 512 threads write mask rows; the 2000th arriver (no
// spinning — provably deadlock-free) runs the 512-thread greedy scan.
// ---------------------------------------------------------------------------
__global__ __launch_bounds__(512) void mask_scan_k(Ws* __restrict__ ws) {
    __shared__ __align__(16) u64 sbuf[2][TROWS * NWORD];
    __shared__ int s_stop;
    __shared__ int s_last;
    const int tid = threadIdx.x;
    const int lane = tid & 63;
    const int wave = tid >> 6;

    // ---- mask phase: one row i per block, 8 waves over 32 words ----
    {
        const int i = blockIdx.x;
        const float4 bi = ws->cand[i];
        const float ai = (bi.z - bi.x) * (bi.w - bi.y);
        for (int wd = wave; wd < NWORD; wd += 8) {
            int j = wd * 64 + lane;
            bool bit = false;
            if (j < K_PRE && j > i) {
                float4 bj = ws->cand[j];
                float aj = (bj.z - bj.x) * (bj.w - bj.y);
                float xx1 = fmaxf(bi.x, bj.x);
                float yy1 = fmaxf(bi.y, bj.y);
                float xx2 = fminf(bi.z, bj.z);
                float yy2 = fminf(bi.w, bj.w);
                float ww = fmaxf(xx2 - xx1, 0.0f);
                float hh = fmaxf(yy2 - yy1, 0.0f);
                float inter = ww * hh;
                float iou = inter / (ai + aj - inter + 1e-6f);
                bit = iou > IOU_THR;
            }
            u64 bal = __ballot(bit);
            if (lane == 0) ws->mask[(size_t)i * NWORD + wd] = bal;
        }
    }

    // ---- last-block ticket ----
    __syncthreads();
    if (tid == 0) {
        __threadfence();                          // release mask rows
        uint32_t old = atomicAdd(&ws->T, 1u);
        s_last = (old == K_PRE - 1) ? 1 : 0;
    }
    __syncthreads();
    if (!s_last) return;
    if (tid == 0) __threadfence();                // acquire all mask rows
    __syncthreads();

    // ---- scan phase (512 threads of the last block) ----
    const int lmod = lane & 31;
    const u64* __restrict__ mask = ws->mask;
    {
        const ulonglong2* src = (const ulonglong2*)mask;
        ulonglong2* dst = (ulonglong2*)sbuf[0];
        for (int e = tid; e < TROWS * NWORD / 2; e += 512) dst[e] = src[e];
    }
    if (tid == 0) s_stop = 0;
    __syncthreads();

    u64 supp = 0ull;
    int kcnt = 0;
    int decided = 0;
    for (int t = 0; t < NTILE; ++t) {
        const int base = t * TROWS;
        const int nb = min(TROWS, K_PRE - base);
        if (wave == 0) {
            const u64* sm = sbuf[t & 1];
            u64 A[CH], B[CH];
#pragma unroll
            for (int b = 0; b < CH; ++b) A[b] = sm[b * NWORD + lmod];
            for (int s = 0; s < nb; s += 2 * CH) {
                const bool hasB = (s + CH) < nb;
                if (hasB) {
#pragma unroll
                    for (int b = 0; b < CH; ++b) B[b] = sm[(s + CH + b) * NWORD + lmod];
                }
                {
                    const int w = (base + s) >> 6;
                    const int bofs = (base + s) & 63;
                    u64 keptw = 0ull;
                    if (lane == w) {
                        u64 cur = supp;
#pragma unroll
                        for (int b = 0; b < CH; ++b) {
                            u64 bit = (cur >> (bofs + b)) & 1ull;
                            u64 sel = bit - 1ull;
                            cur |= A[b] & sel;
                            keptw |= sel & (1ull << b);
                        }
                        supp = cur;
                    }
                    u64 kb = __shfl(keptw, w);
                    kcnt += __popcll(kb);
#pragma unroll
                    for (int b = 0; b < CH; ++b) {
                        u64 sel = 0ull - ((kb >> b) & 1ull);
                        supp |= A[b] & sel;
                    }
                }
                if (hasB) {
                    if (s + 2 * CH < nb) {
#pragma unroll
                        for (int b = 0; b < CH; ++b)
                            A[b] = sm[(s + 2 * CH + b) * NWORD + lmod];
                    }
                    const int w = (base + s + CH) >> 6;
                    const int bofs = (base + s + CH) & 63;
                    u64 keptw = 0ull;
                    if (lane == w) {
                        u64 cur = supp;
#pragma unroll
                        for (int b = 0; b < CH; ++b) {
                            u64 bit = (cur >> (bofs + b)) & 1ull;
                            u64 sel = bit - 1ull;
                            cur |= B[b] & sel;
                            keptw |= sel & (1ull << b);
                        }
                        supp = cur;
                    }
                    u64 kb = __shfl(keptw, w);
                    kcnt += __popcll(kb);
#pragma unroll
                    for (int b = 0; b < CH; ++b) {
                        u64 sel = 0ull - ((kb >> b) & 1ull);
                        supp |= B[b] & sel;
                    }
                }
            }
            decided = base + nb;
            if (lane == 0 && kcnt >= K_POST) s_stop = 1;
        } else if (t + 1 < NTILE) {
            const int nbase = (t + 1) * TROWS;
            const int npairs = (min(TROWS, K_PRE - nbase) * NWORD) / 2;
            const ulonglong2* src = (const ulonglong2*)(mask + (size_t)nbase * NWORD);
            ulonglong2* dst = (ulonglong2*)sbuf[(t + 1) & 1];
            for (int e = tid - 64; e < npairs; e += 448) dst[e] = src[e];
        }
        __syncthreads();
        if (s_stop) break;
    }

    if (wave == 0) {
        u64 valid;
        if (lane < NWORD - 1)       valid = ~0ull;
        else if (lane == NWORD - 1) valid = (1ull << (K_PRE - (NWORD - 1) * 64)) - 1ull;
        else                        valid = 0ull;
        const int dw = decided - lane * 64;
        const u64 dmask = (dw <= 0) ? 0ull : ((dw >= 64) ? ~0ull : ((1ull << dw) - 1ull));
        u64 keepw = (~supp) & valid & dmask;
        int cnt = __popcll(keepw);
        int incl = cnt;
        for (int off = 1; off < 64; off <<= 1) {
            int t = __shfl_up(incl, off);
            if (lane >= off) incl += t;
        }
        int pos = incl - cnt;
        u64 kw = keepw;
        while (kw) {
            int b = __ffsll((unsigned long long)kw) - 1;
            kw &= kw - 1ull;
            if (pos < K_POST) ws->rows[pos] = lane * 64 + b;
            ++pos;
        }
        int total = __shfl(incl, 63);
        if (lane == 0) ws->nk = total;
        int start = total < K_POST ? total : K_POST;
        for (int r = start + lane; r < K_POST; r += 64) ws->rows[r] = -1;
    }
}

// ---------------------------------------------------------------------------
// Kernel 3: ROIAlign — byte-identical to round-2 (44us, FETCH 20.4MB).
// ---------------------------------------------------------------------------
__global__ __launch_bounds__(256) void roi_k(const float* __restrict__ feat,
                                             const Ws* __restrict__ ws,
                                             float* __restrict__ out) {
    const int b = blockIdx.x;
    const int xcd = b & 7;
    const int s = b >> 3;
    const int r = s & (K_POST - 1);
    const int cg = xcd + 8 * (s >> 9);
    const int cbase = cg * CG;
    float* oblk = out + (size_t)r * (FC * 49) + (size_t)cbase * 49;
    const int row = ws->rows[r];
    const int tid = threadIdx.x;

    if (row < 0) {
        for (int e = tid; e < CG * 49; e += 256) oblk[e] = 0.0f;
        return;
    }
    if (tid >= 245) return;                 // 5 channel slots x 49 bins

    const int p = tid % 49;
    const int cslot = tid / 49;             // 0..4
    const int oy = p / 7, ox = p % 7;

    const float4 bx = ws->cand[row];
    const float x1 = bx.x * SCALE, y1 = bx.y * SCALE;
    const float x2 = bx.z * SCALE, y2 = bx.w * SCALE;
    const float rw = fmaxf(x2 - x1, 1.0f);
    const float rh = fmaxf(y2 - y1, 1.0f);
    const float stepx = rw / 14.0f;
    const float stepy = rh / 14.0f;

    int    off0[4], off1[4];
    float4 w4[4];
#pragma unroll
    for (int sub = 0; sub < 4; ++sub) {
        const int sy = sub >> 1, sx = sub & 1;
        float yy = y1 + ((float)(2 * oy + sy) + 0.5f) * stepy;
        float y = fminf(fmaxf(yy, 0.0f), (float)(FH - 1));
        float fy0 = floorf(y);
        int iy0 = (int)fy0;
        int iy1 = min(iy0 + 1, FH - 1);
        float ly = y - fy0;
        float xx = x1 + ((float)(2 * ox + sx) + 0.5f) * stepx;
        float x = fminf(fmaxf(xx, 0.0f), (float)(FW - 1));
        float fx0 = floorf(x);
        int ix0 = (int)fx0;
        float lx = x - fx0;
        float wxl, wxr; int base;
        if (ix0 >= FW - 1) { base = FW - 2; wxl = 0.0f; wxr = 1.0f; }
        else               { base = ix0;    wxl = 1.0f - lx; wxr = lx; }
        float wy0 = 1.0f - ly, wy1 = ly;
        off0[sub] = iy0 * FW + base;
        off1[sub] = iy1 * FW + base;
        w4[sub] = make_float4(wy0 * wxl * 0.25f, wy0 * wxr * 0.25f,
                              wy1 * wxl * 0.25f, wy1 * wxr * 0.25f);
    }

    const float* fb = feat + (size_t)cbase * (FH * FW);
    const float* f0 = fb + (size_t)cslot * (FH * FW);
    const float* f1 = fb + (size_t)(cslot + 5) * (FH * FW);
    const float* f2 = fb + (size_t)(cslot + 10) * (FH * FW);
    f2u r0[8], r1[8], r2[8], r3[8];
#pragma unroll
    for (int sub = 0; sub < 4; ++sub) {
        r0[2 * sub]     = *(const f2u*)(f0 + off0[sub]);
        r0[2 * sub + 1] = *(const f2u*)(f0 + off1[sub]);
    }
#pragma unroll
    for (int sub = 0; sub < 4; ++sub) {
        r1[2 * sub]     = *(const f2u*)(f1 + off0[sub]);
        r1[2 * sub + 1] = *(const f2u*)(f1 + off1[sub]);
    }
#pragma unroll
    for (int sub = 0; sub < 4; ++sub) {
        r2[2 * sub]     = *(const f2u*)(f2 + off0[sub]);
        r2[2 * sub + 1] = *(const f2u*)(f2 + off1[sub]);
    }
    const bool has4 = (cslot == 0);
    if (has4) {
        const float* f3 = fb + (size_t)15 * (FH * FW);
#pragma unroll
        for (int sub = 0; sub < 4; ++sub) {
            r3[2 * sub]     = *(const f2u*)(f3 + off0[sub]);
            r3[2 * sub + 1] = *(const f2u*)(f3 + off1[sub]);
        }
    }

    float a0 = 0.0f, a1 = 0.0f, a2 = 0.0f;
#pragma unroll
    for (int sub = 0; sub < 4; ++sub) {
        a0 += w4[sub].x * r0[2 * sub].x + w4[sub].y * r0[2 * sub].y
            + w4[sub].z * r0[2 * sub + 1].x + w4[sub].w * r0[2 * sub + 1].y;
    }
#pragma unroll
    for (int sub = 0; sub < 4; ++sub) {
        a1 += w4[sub].x * r1[2 * sub].x + w4[sub].y * r1[2 * sub].y
            + w4[sub].z * r1[2 * sub + 1].x + w4[sub].w * r1[2 * sub + 1].y;
    }
#pragma unroll
    for (int sub = 0; sub < 4; ++sub) {
        a2 += w4[sub].x * r2[2 * sub].x + w4[sub].y * r2[2 * sub].y
            + w4[sub].z * r2[2 * sub + 1].x + w4[sub].w * r2[2 * sub + 1].y;
    }
    oblk[cslot * 49 + p] = a0;
    oblk[(cslot + 5) * 49 + p] = a1;
    oblk[(cslot + 10) * 49 + p] = a2;

    if (has4) {
        float a3 = 0.0f;
#pragma unroll
        for (int sub = 0; sub < 4; ++sub) {
            a3 += w4[sub].x * r3[2 * sub].x + w4[sub].y * r3[2 * sub].y
                + w4[sub].z * r3[2 * sub + 1].x + w4[sub].w * r3[2 * sub + 1].y;
        }
        oblk[15 * 49 + p] = a3;
    }
}

extern "C" void kernel_launch(void* const* d_in, const int* in_sizes, int n_in,
                              void* d_out, int out_size, void* d_ws, size_t ws_size,
                              hipStream_t stream) {
    const float* feature    = (const float*)d_in[0];
    const float* objectness = (const float*)d_in[1];
    const float* deltas     = (const float*)d_in[2];
    const float* anchors    = (const float*)d_in[3];
    Ws* ws = (Ws*)d_ws;
    float* out = (float*)d_out;

    // Zero the 3 sel_k barrier counters (live just past the hist alias in
    // the mask region). Workspace is NOT re-poisoned between graph replays,
    // so this must be an explicit node; 12B memset is the cheapest option.
    hipMemsetAsync((char*)d_ws + offsetof(Ws, mask) + (size_t)HBINS * 4, 0, 12, stream);

    hipLaunchKernelGGL(sel_k, dim3(SEL_NB), dim3(256), 0, stream,
                       objectness, deltas, anchors, ws);
    hipLaunchKernelGGL(mask_scan_k, dim3(K_PRE), dim3(512), 0, stream, ws);
    hipLaunchKernelGGL(roi_k, dim3(16 * K_POST), dim3(256), 0, stream, feature, ws, out);
}

// Round 6
// 200.752 us; speedup vs baseline: 2.4931x; 1.2560x over previous
//
#include <hip/hip_runtime.h>
#include <cstdint>
#include <cstddef>

#define N_ANCH   120000
#define K_PRE    2000
#define K_POST   512
#define CAP      4096
#define NWORD    32          // ceil(K_PRE/64)
#define HBINS    4096        // top-12-bit histogram
#define IOU_THR  0.7f
#define IMGF     800.0f
#define CLIPV    4.135166556742356f
#define FH       200
#define FW       200
#define FC       256
#define SCALE    0.25f

#define TROWS    96          // scan tile rows (96*256B = 24KB; x2 buffers = 48KB LDS)
#define NTILE    21          // ceil(2000/96); last tile = 80 rows
#define CH       8           // scan chunk rows (register prefetch depth)

#define CG       16          // roi: channels per group
#define TPE      4           // rank: threads per element

typedef unsigned long long u64;
typedef float f2u __attribute__((ext_vector_type(2), aligned(4)));

struct Ws {
    uint32_t T;          // PROGRESS counter: #rows published (scan -> roi handoff)
    uint32_t cnt;        // gather counter
    int32_t  nk;         // number kept after NMS
    uint32_t pad;
    u64      combo[CAP];             // (~key)<<32 | index (unsorted)
    float4   cand[K_PRE];            // decoded candidate boxes, score-desc order
    int      rows[K_POST];           // candidate rank per output row, -1 = invalid
    u64      mask[(size_t)K_PRE * NWORD];  // IoU bitmask
    // NOTE: first 16KB of mask doubles as the uint32 hist[4096] (used before mask)
};

// Monotonic float -> uint key (larger float => larger uint). No NaNs expected.
__device__ inline uint32_t fkey(float f) {
    uint32_t u = __float_as_uint(f);
    return (u & 0x80000000u) ? ~u : (u | 0x80000000u);
}

// ---------------------------------------------------------------------------
// Kernel 0: zero the histogram (aliased onto mask region) + counters.
// T=0 is REQUIRED before scan_roi_k's consumers poll it.
// ---------------------------------------------------------------------------
__global__ __launch_bounds__(1024) void zero_k(Ws* __restrict__ ws) {
    uint32_t* h = (uint32_t*)ws->mask;
    for (int i = threadIdx.x; i < HBINS; i += 1024) h[i] = 0u;
    if (threadIdx.x == 0) { ws->cnt = 0u; ws->nk = 0; ws->T = 0u; }
}

// ---------------------------------------------------------------------------
// Kernel 1: grid-wide 4096-bin histogram of top-12 key bits (LDS-privatized).
// ---------------------------------------------------------------------------
__global__ __launch_bounds__(256) void hist_k(const float* __restrict__ obj,
                                              uint32_t* __restrict__ hist) {
    __shared__ uint32_t h[HBINS];
    for (int i = threadIdx.x; i < HBINS; i += 256) h[i] = 0u;
    __syncthreads();
    const float4* o4 = (const float4*)obj;
    for (int i = blockIdx.x * 256 + threadIdx.x; i < N_ANCH / 4; i += gridDim.x * 256) {
        float4 v = o4[i];
        atomicAdd(&h[fkey(v.x) >> 20], 1u);
        atomicAdd(&h[fkey(v.y) >> 20], 1u);
        atomicAdd(&h[fkey(v.z) >> 20], 1u);
        atomicAdd(&h[fkey(v.w) >> 20], 1u);
    }
    __syncthreads();
    for (int i = threadIdx.x; i < HBINS; i += 256)
        if (h[i]) atomicAdd(&hist[i], h[i]);
}

// ---------------------------------------------------------------------------
// Kernel 2 (fused resolve+gather).
// ---------------------------------------------------------------------------
__global__ __launch_bounds__(256) void gather_k(const float* __restrict__ obj,
                                                const uint32_t* __restrict__ hist,
                                                Ws* __restrict__ ws) {
    __shared__ uint32_t wsum[4];
    __shared__ uint32_t sT;
    const int tid = threadIdx.x;
    const int lane = tid & 63, wave = tid >> 6;
    uint32_t c[16]; uint32_t s = 0;
#pragma unroll
    for (int k = 0; k < 16; ++k) { c[k] = hist[HBINS - 1 - (16 * tid + k)]; s += c[k]; }
    uint32_t incl = s;
    for (int off = 1; off < 64; off <<= 1) {
        uint32_t t = __shfl_up(incl, off);
        if (lane >= off) incl += t;
    }
    if (lane == 63) wsum[wave] = incl;
    __syncthreads();
    uint32_t wpre = 0;
    for (int w2 = 0; w2 < wave; ++w2) wpre += wsum[w2];
    uint32_t before = wpre + incl - s;
#pragma unroll
    for (int k = 0; k < 16; ++k) {
        uint32_t after = before + c[k];
        if (before < K_PRE && after >= K_PRE)
            sT = (uint32_t)(HBINS - 1 - (16 * tid + k)) << 20;
        before = after;
    }
    __syncthreads();
    const uint32_t T = sT;
    int i = blockIdx.x * 256 + tid;
    if (i >= N_ANCH / 4) return;
    float4 v = ((const float4*)obj)[i];
    float vals[4] = {v.x, v.y, v.z, v.w};
#pragma unroll
    for (int k = 0; k < 4; ++k) {
        uint32_t u = fkey(vals[k]);
        if (u >= T) {
            uint32_t pos = atomicAdd(&ws->cnt, 1u);
            if (pos < CAP)
                ws->combo[pos] = ((u64)(~u) << 32) | (uint32_t)(4 * i + k);
        }
    }
}

// ---------------------------------------------------------------------------
// Kernel 3: RANK-based ordering + decode.
// ---------------------------------------------------------------------------
__global__ __launch_bounds__(256) void rank_decode_k(const float* __restrict__ deltas,
                                                     const float* __restrict__ anchors,
                                                     Ws* __restrict__ ws) {
    __shared__ u64 sc[CAP];
    const int tid = threadIdx.x;
    int M = (int)ws->cnt;
    if (M > CAP) M = CAP;
    const int ebase = blockIdx.x * (256 / TPE);
    if (ebase >= M) return;
    for (int e = tid; e < M; e += 256) sc[e] = ws->combo[e];
    __syncthreads();
    const int gid = ebase + tid / TPE;
    const int sub = tid & (TPE - 1);
    if (gid >= M) return;
    const u64 mine = sc[gid];
    int cnt = 0;
    int j = sub;
    for (; j + 3 * TPE < M; j += 4 * TPE) {
        u64 a = sc[j], b = sc[j + TPE], c = sc[j + 2 * TPE], d = sc[j + 3 * TPE];
        cnt += (int)(a < mine) + (int)(b < mine) + (int)(c < mine) + (int)(d < mine);
    }
    for (; j < M; j += TPE) cnt += (int)(sc[j] < mine);
    cnt += __shfl_xor(cnt, 1);
    cnt += __shfl_xor(cnt, 2);
    if (sub == 0 && cnt < K_PRE) {
        const uint32_t idx = (uint32_t)(mine & 0xFFFFFFFFull);
        float a0 = anchors[idx * 4 + 0], a1 = anchors[idx * 4 + 1];
        float a2 = anchors[idx * 4 + 2], a3 = anchors[idx * 4 + 3];
        float d0 = deltas[idx * 4 + 0],  d1 = deltas[idx * 4 + 1];
        float d2 = fminf(deltas[idx * 4 + 2], CLIPV);
        float d3 = fminf(deltas[idx * 4 + 3], CLIPV);
        float w = a2 - a0, h = a3 - a1;
        float cx = a0 + 0.5f * w, cy = a1 + 0.5f * h;
        float pcx = d0 * w + cx, pcy = d1 * h + cy;
        float pw = expf(d2) * w, ph = expf(d3) * h;
        float x1 = fminf(fmaxf(pcx - 0.5f * pw, 0.0f), IMGF);
        float y1 = fminf(fmaxf(pcy - 0.5f * ph, 0.0f), IMGF);
        float x2 = fminf(fmaxf(pcx + 0.5f * pw, 0.0f), IMGF);
        float y2 = fminf(fmaxf(pcy + 0.5f * ph, 0.0f), IMGF);
        ws->cand[cnt] = make_float4(x1, y1, x2, y2);
    }
}

// ---------------------------------------------------------------------------
// Kernel 4: build the pairwise suppression bitmask.
// ---------------------------------------------------------------------------
__global__ __launch_bounds__(256) void nms_mask_k(Ws* __restrict__ ws) {
    const int i = blockIdx.x;
    const int lane = threadIdx.x & 63;
    const int wave = threadIdx.x >> 6;
    const float4 bi = ws->cand[i];
    const float ai = (bi.z - bi.x) * (bi.w - bi.y);
    for (int wd = wave; wd < NWORD; wd += 4) {
        int j = wd * 64 + lane;
        bool bit = false;
        if (j < K_PRE && j > i) {
            float4 bj = ws->cand[j];
            float aj = (bj.z - bj.x) * (bj.w - bj.y);
            float xx1 = fmaxf(bi.x, bj.x);
            float yy1 = fmaxf(bi.y, bj.y);
            float xx2 = fminf(bi.z, bj.z);
            float yy2 = fminf(bi.w, bj.w);
            float ww = fmaxf(xx2 - xx1, 0.0f);
            float hh = fmaxf(yy2 - yy1, 0.0f);
            float inter = ww * hh;
            float iou = inter / (ai + aj - inter + 1e-6f);
            bit = iou > IOU_THR;
        }
        u64 bal = __ballot(bit);
        if (lane == 0) ws->mask[(size_t)i * NWORD + wd] = bal;
    }
}

// ---------------------------------------------------------------------------
// Kernel 5 (round-6 = round-5 with the GRID-SIZE FIX): fused scan + ROIAlign
// with streaming handoff.
//  - Block 0: greedy scan; publishes rows[] INCREMENTALLY per tile via
//    agent-scope atomic stores, then release-bumps progress ws->T. Ends at
//    T=K_POST always (tail -1 fill) — deadlock-free.
//  - Blocks 1..4096: u=bid-1; r=u>>3 in [0,512); halves (tid>>8) cover
//    cg = (u&7) and (u&7)+8. Lane 0 spin-sleeps until T > r, then the
//    proven round-2 roi body runs. In-order dispatch => roi streams behind
//    the scan front.
//  ROUND-5 BUG: launched 1+8*K_POST/2 = 2049 blocks => r only reached 255;
//  ROIs 256-511 never written (absmax fail). Correct grid = 1 + 8*K_POST.
// ---------------------------------------------------------------------------
__global__ __launch_bounds__(512) void scan_roi_k(const float* __restrict__ feat,
                                                  Ws* __restrict__ ws,
                                                  float* __restrict__ out) {
    __shared__ __align__(16) u64 sbuf[2][TROWS * NWORD];
    __shared__ int s_stop;
    __shared__ int sRow;
    const int tid = threadIdx.x;
    const int lane = tid & 63;
    const int wave = tid >> 6;

    if (blockIdx.x == 0) {
        // ===================== SCAN (producer) =====================
        const int lmod = lane & 31;
        const u64* __restrict__ mask = ws->mask;
        {
            const ulonglong2* src = (const ulonglong2*)mask;
            ulonglong2* dst = (ulonglong2*)sbuf[0];
            for (int e = tid; e < TROWS * NWORD / 2; e += 512) dst[e] = src[e];
        }
        if (tid == 0) s_stop = 0;
        __syncthreads();

        u64 supp = 0ull;
        int pubtot = 0;                      // rows published so far
        const u64 valid = (lane < NWORD - 1) ? ~0ull
                        : (lane == NWORD - 1 ? ((1ull << (K_PRE - (NWORD - 1) * 64)) - 1ull)
                                             : 0ull);
        for (int t = 0; t < NTILE; ++t) {
            const int base = t * TROWS;
            const int nb = min(TROWS, K_PRE - base);
            if (wave == 0) {
                const u64* sm = sbuf[t & 1];
                u64 A[CH], B[CH];
#pragma unroll
                for (int b = 0; b < CH; ++b) A[b] = sm[b * NWORD + lmod];
                for (int s = 0; s < nb; s += 2 * CH) {
                    const bool hasB = (s + CH) < nb;
                    if (hasB) {
#pragma unroll
                        for (int b = 0; b < CH; ++b) B[b] = sm[(s + CH + b) * NWORD + lmod];
                    }
                    {
                        const int w = (base + s) >> 6;
                        const int bofs = (base + s) & 63;
                        u64 keptw = 0ull;
                        if (lane == w) {
                            u64 cur = supp;
#pragma unroll
                            for (int b = 0; b < CH; ++b) {
                                u64 bit = (cur >> (bofs + b)) & 1ull;
                                u64 sel = bit - 1ull;
                                cur |= A[b] & sel;
                                keptw |= sel & (1ull << b);
                            }
                            supp = cur;
                        }
                        u64 kb = __shfl(keptw, w);
#pragma unroll
                        for (int b = 0; b < CH; ++b) {
                            u64 sel = 0ull - ((kb >> b) & 1ull);
                            supp |= A[b] & sel;
                        }
                    }
                    if (hasB) {
                        if (s + 2 * CH < nb) {
#pragma unroll
                            for (int b = 0; b < CH; ++b)
                                A[b] = sm[(s + 2 * CH + b) * NWORD + lmod];
                        }
                        const int w = (base + s + CH) >> 6;
                        const int bofs = (base + s + CH) & 63;
                        u64 keptw = 0ull;
                        if (lane == w) {
                            u64 cur = supp;
#pragma unroll
                            for (int b = 0; b < CH; ++b) {
                                u64 bit = (cur >> (bofs + b)) & 1ull;
                                u64 sel = bit - 1ull;
                                cur |= B[b] & sel;
                                keptw |= sel & (1ull << b);
                            }
                            supp = cur;
                        }
                        u64 kb = __shfl(keptw, w);
#pragma unroll
                        for (int b = 0; b < CH; ++b) {
                            u64 sel = 0ull - ((kb >> b) & 1ull);
                            supp |= B[b] & sel;
                        }
                    }
                }
                // ---- incremental publish of rows decided in [base, base+nb) ----
                {
                    const int w0 = lane << 6;
                    int lo = base - w0;      if (lo < 0)  lo = 0;
                    int hi = base + nb - w0; if (hi > 64) hi = 64;
                    u64 rmask = 0ull;
                    if (hi > lo) {
                        u64 mh = (hi >= 64) ? ~0ull : ((1ull << hi) - 1ull);
                        u64 ml = (lo <= 0) ? 0ull : ((1ull << lo) - 1ull);
                        rmask = mh & ~ml;
                    }
                    u64 keepn = (~supp) & valid & rmask;
                    int c = __popcll(keepn);
                    int incl = c;
                    for (int off = 1; off < 64; off <<= 1) {
                        int tt = __shfl_up(incl, off);
                        if (lane >= off) incl += tt;
                    }
                    int pos = pubtot + incl - c;
                    u64 kw = keepn;
                    while (kw) {
                        int b = __ffsll((unsigned long long)kw) - 1;
                        kw &= kw - 1ull;
                        if (pos < K_POST)
                            __hip_atomic_store(&ws->rows[pos], w0 + b,
                                               __ATOMIC_RELAXED, __HIP_MEMORY_SCOPE_AGENT);
                        ++pos;
                    }
                    pubtot += __shfl(incl, 63);
                    int pr = pubtot < K_POST ? pubtot : K_POST;
                    if (lane == 0) {
                        __hip_atomic_store(&ws->T, (uint32_t)pr,
                                           __ATOMIC_RELEASE, __HIP_MEMORY_SCOPE_AGENT);
                        if (pubtot >= K_POST) s_stop = 1;
                    }
                }
            } else if (t + 1 < NTILE) {
                const int nbase = (t + 1) * TROWS;
                const int npairs = (min(TROWS, K_PRE - nbase) * NWORD) / 2;
                const ulonglong2* src = (const ulonglong2*)(mask + (size_t)nbase * NWORD);
                ulonglong2* dst = (ulonglong2*)sbuf[(t + 1) & 1];
                for (int e = tid - 64; e < npairs; e += 448) dst[e] = src[e];
            }
            __syncthreads();
            if (s_stop) break;
        }

        if (wave == 0) {
            for (int rr = pubtot + lane; rr < K_POST; rr += 64)
                __hip_atomic_store(&ws->rows[rr], -1,
                                   __ATOMIC_RELAXED, __HIP_MEMORY_SCOPE_AGENT);
            if (lane == 0) {
                ws->nk = pubtot;
                __hip_atomic_store(&ws->T, (uint32_t)K_POST,
                                   __ATOMIC_RELEASE, __HIP_MEMORY_SCOPE_AGENT);
            }
        }
        return;
    }

    // ===================== ROI (consumers) =====================
    const int u = (int)blockIdx.x - 1;       // 0..4095
    const int r = u >> 3;                    // roi index 0..511, increases with bid
    const int xcd = u & 7;
    const int h = tid >> 8;                  // half: 0 or 1
    const int tid2 = tid & 255;
    const int cg = xcd + 8 * h;              // halves cover cg and cg+8
    const int cbase = cg * CG;

    if (tid == 0) {
        while (__hip_atomic_load(&ws->T, __ATOMIC_RELAXED, __HIP_MEMORY_SCOPE_AGENT)
               <= (uint32_t)r)
            __builtin_amdgcn_s_sleep(16);
        (void)__hip_atomic_load(&ws->T, __ATOMIC_ACQUIRE, __HIP_MEMORY_SCOPE_AGENT);
        sRow = __hip_atomic_load(&ws->rows[r], __ATOMIC_RELAXED, __HIP_MEMORY_SCOPE_AGENT);
    }
    __syncthreads();
    const int row = sRow;
    float* oblk = out + (size_t)r * (FC * 49) + (size_t)cbase * 49;

    if (row < 0) {
        for (int e = tid2; e < CG * 49; e += 256) oblk[e] = 0.0f;
        return;
    }
    if (tid2 >= 245) return;                 // 5 channel slots x 49 bins per half

    const int p = tid2 % 49;
    const int cslot = tid2 / 49;             // 0..4
    const int oy = p / 7, ox = p % 7;

    const float4 bx = ws->cand[row];
    const float x1 = bx.x * SCALE, y1 = bx.y * SCALE;
    const float x2 = bx.z * SCALE, y2 = bx.w * SCALE;
    const float rw = fmaxf(x2 - x1, 1.0f);
    const float rh = fmaxf(y2 - y1, 1.0f);
    const float stepx = rw / 14.0f;
    const float stepy = rh / 14.0f;

    int    off0[4], off1[4];
    float4 w4[4];
#pragma unroll
    for (int sub = 0; sub < 4; ++sub) {
        const int sy = sub >> 1, sx = sub & 1;
        float yy = y1 + ((float)(2 * oy + sy) + 0.5f) * stepy;
        float y = fminf(fmaxf(yy, 0.0f), (float)(FH - 1));
        float fy0 = floorf(y);
        int iy0 = (int)fy0;
        int iy1 = min(iy0 + 1, FH - 1);
        float ly = y - fy0;
        float xx = x1 + ((float)(2 * ox + sx) + 0.5f) * stepx;
        float x = fminf(fmaxf(xx, 0.0f), (float)(FW - 1));
        float fx0 = floorf(x);
        int ix0 = (int)fx0;
        float lx = x - fx0;
        float wxl, wxr; int base;
        if (ix0 >= FW - 1) { base = FW - 2; wxl = 0.0f; wxr = 1.0f; }
        else               { base = ix0;    wxl = 1.0f - lx; wxr = lx; }
        float wy0 = 1.0f - ly, wy1 = ly;
        off0[sub] = iy0 * FW + base;
        off1[sub] = iy1 * FW + base;
        w4[sub] = make_float4(wy0 * wxl * 0.25f, wy0 * wxr * 0.25f,
                              wy1 * wxl * 0.25f, wy1 * wxr * 0.25f);
    }

    // ---- ISSUE PHASE: all scattered loads back-to-back.
    const float* fb = feat + (size_t)cbase * (FH * FW);
    const float* f0 = fb + (size_t)cslot * (FH * FW);
    const float* f1 = fb + (size_t)(cslot + 5) * (FH * FW);
    const float* f2 = fb + (size_t)(cslot + 10) * (FH * FW);
    f2u r0[8], r1[8], r2[8], r3[8];
#pragma unroll
    for (int sub = 0; sub < 4; ++sub) {
        r0[2 * sub]     = *(const f2u*)(f0 + off0[sub]);
        r0[2 * sub + 1] = *(const f2u*)(f0 + off1[sub]);
    }
#pragma unroll
    for (int sub = 0; sub < 4; ++sub) {
        r1[2 * sub]     = *(const f2u*)(f1 + off0[sub]);
        r1[2 * sub + 1] = *(const f2u*)(f1 + off1[sub]);
    }
#pragma unroll
    for (int sub = 0; sub < 4; ++sub) {
        r2[2 * sub]     = *(const f2u*)(f2 + off0[sub]);
        r2[2 * sub + 1] = *(const f2u*)(f2 + off1[sub]);
    }
    const bool has4 = (cslot == 0);
    if (has4) {
        const float* f3 = fb + (size_t)15 * (FH * FW);
#pragma unroll
        for (int sub = 0; sub < 4; ++sub) {
            r3[2 * sub]     = *(const f2u*)(f3 + off0[sub]);
            r3[2 * sub + 1] = *(const f2u*)(f3 + off1[sub]);
        }
    }

    // ---- COMPUTE PHASE: FMAs in load-issue order.
    float a0 = 0.0f, a1 = 0.0f, a2 = 0.0f;
#pragma unroll
    for (int sub = 0; sub < 4; ++sub) {
        a0 += w4[sub].x * r0[2 * sub].x + w4[sub].y * r0[2 * sub].y
            + w4[sub].z * r0[2 * sub + 1].x + w4[sub].w * r0[2 * sub + 1].y;
    }
#pragma unroll
    for (int sub = 0; sub < 4; ++sub) {
        a1 += w4[sub].x * r1[2 * sub].x + w4[sub].y * r1[2 * sub].y
            + w4[sub].z * r1[2 * sub + 1].x + w4[sub].w * r1[2 * sub + 1].y;
    }
#pragma unroll
    for (int sub = 0; sub < 4; ++sub) {
        a2 += w4[sub].x * r2[2 * sub].x + w4[sub].y * r2[2 * sub].y
            + w4[sub].z * r2[2 * sub + 1].x + w4[sub].w * r2[2 * sub + 1].y;
    }
    oblk[cslot * 49 + p] = a0;
    oblk[(cslot + 5) * 49 + p] = a1;
    oblk[(cslot + 10) * 49 + p] = a2;

    if (has4) {
        float a3 = 0.0f;
#pragma unroll
        for (int sub = 0; sub < 4; ++sub) {
            a3 += w4[sub].x * r3[2 * sub].x + w4[sub].y * r3[2 * sub].y
                + w4[sub].z * r3[2 * sub + 1].x + w4[sub].w * r3[2 * sub + 1].y;
        }
        oblk[15 * 49 + p] = a3;
    }
}

extern "C" void kernel_launch(void* const* d_in, const int* in_sizes, int n_in,
                              void* d_out, int out_size, void* d_ws, size_t ws_size,
                              hipStream_t stream) {
    const float* feature    = (const float*)d_in[0];
    const float* objectness = (const float*)d_in[1];
    const float* deltas     = (const float*)d_in[2];
    const float* anchors    = (const float*)d_in[3];
    Ws* ws = (Ws*)d_ws;
    uint32_t* hist = (uint32_t*)ws->mask;   // alias: hist lives in (pre-)mask space
    float* out = (float*)d_out;

    hipLaunchKernelGGL(zero_k, dim3(1), dim3(1024), 0, stream, ws);
    hipLaunchKernelGGL(hist_k, dim3(256), dim3(256), 0, stream, objectness, hist);
    hipLaunchKernelGGL(gather_k, dim3((N_ANCH / 4 + 255) / 256), dim3(256), 0, stream,
                       objectness, hist, ws);
    hipLaunchKernelGGL(rank_decode_k, dim3(CAP / (256 / TPE)), dim3(256), 0, stream,
                       deltas, anchors, ws);
    hipLaunchKernelGGL(nms_mask_k, dim3(K_PRE), dim3(256), 0, stream, ws);
    hipLaunchKernelGGL(scan_roi_k, dim3(1 + 8 * K_POST), dim3(512), 0, stream,
                       feature, ws, out);
}